// Round 1
// baseline (2146.761 us; speedup 1.0000x reference)
//
#include <hip/hip_runtime.h>
#include <math.h>

#define B_    2048
#define V_    5023
#define N3    15069      // V*3
#define NSE   400        // NS+NE
#define KTOT  440        // 400 betas + 36 pose_feature + 4 pad
#define VOFF  30861312   // B_*N3, start of rot_mats in d_out

// ws layout (floats)
#define OFF_C    0          // [B][440]   betas|pf|pad
#define OFF_PDT  901120     // [15069][40] pose_dirs^T padded
#define OFF_JSP  1503880    // [8][15*400] partial JS
#define OFF_JTP  1551880    // [8][15]     partial Jt
#define OFF_JS   1552000    // [15*400]
#define OFF_JT   1558000    // [15]
#define OFF_A    1558016    // [B][5][12]  blended-transform source mats

// ---------------- K2a: partial JS = Jreg @ shape_dirs, Jt = Jreg @ v_template
__global__ void k_js_partial(const float* __restrict__ Jreg, const float* __restrict__ SD,
                             const float* __restrict__ VT, float* __restrict__ ws) {
    int jk = blockIdx.x;            // 0..14  (j*3+k)
    int ch = blockIdx.y;            // 0..7   v-chunk
    int j = jk / 3, k = jk % 3;
    int t = threadIdx.x;            // 0..511
    int v0 = ch * 628;
    int v1 = min(V_, v0 + 628);
    float acc = 0.f;
    if (t < NSE) {
        for (int v = v0; v < v1; ++v) {
            float jr = Jreg[j * V_ + v];
            acc += jr * SD[(v * 3 + k) * NSE + t];
        }
        ws[OFF_JSP + (ch * 15 + jk) * NSE + t] = acc;
    } else if (t == 511) {
        for (int v = v0; v < v1; ++v) {
            float jr = Jreg[j * V_ + v];
            acc += jr * VT[v * 3 + k];
        }
        ws[OFF_JTP + ch * 15 + jk] = acc;
    }
}

// ---------------- K2c: reduce partials
__global__ void k_js_reduce(float* __restrict__ ws) {
    int t = blockIdx.x * 256 + threadIdx.x;
    if (t < 6000) {
        float s = 0.f;
        for (int ch = 0; ch < 8; ++ch) s += ws[OFF_JSP + ch * 6000 + t];
        ws[OFF_JS + t] = s;
    } else if (t < 6015) {
        int i = t - 6000;
        float s = 0.f;
        for (int ch = 0; ch < 8; ++ch) s += ws[OFF_JTP + ch * 15 + i];
        ws[OFF_JT + i] = s;
    }
}

// ---------------- K2b: transpose pose_dirs [36,15069] -> PDT [15069,40] (pad 36..39 = 0)
__global__ void k_pdt(const float* __restrict__ PD, float* __restrict__ ws) {
    int lp = blockIdx.y;                       // 0..39
    int n = blockIdx.x * 256 + threadIdx.x;
    if (n < N3) ws[OFF_PDT + n * 40 + lp] = (lp < 36) ? PD[lp * N3 + n] : 0.f;
}

// ---------------- K0: c[b][0..439] = [shape | expr | 0...] (pf filled later)
__global__ void k_cbetas(const float* __restrict__ sh, const float* __restrict__ ex,
                         float* __restrict__ ws) {
    int f = blockIdx.x * 256 + threadIdx.x;
    if (f >= B_ * KTOT) return;
    int b = f / KTOT, l = f % KTOT;
    float v = 0.f;
    if (l < 300) v = sh[b * 300 + l];
    else if (l < 400) v = ex[b * 100 + (l - 300)];
    ws[OFF_C + f] = v;
}

// ---------------- rodrigues matching the reference exactly (note +1e-8 on components)
__device__ __forceinline__ void rodrigues(float rx, float ry, float rz, float* R) {
    float ax = rx + 1e-8f, ay = ry + 1e-8f, az = rz + 1e-8f;
    float ang = sqrtf(ax * ax + ay * ay + az * az);
    float inv = 1.f / ang;
    float ux = rx * inv, uy = ry * inv, uz = rz * inv;
    float s = sinf(ang), c = cosf(ang), m = 1.f - c;
    R[0] = 1.f + m * (-uz * uz - uy * uy);
    R[1] = -s * uz + m * ux * uy;
    R[2] =  s * uy + m * ux * uz;
    R[3] =  s * uz + m * ux * uy;
    R[4] = 1.f + m * (-uz * uz - ux * ux);
    R[5] = -s * ux + m * uy * uz;
    R[6] = -s * uy + m * ux * uz;
    R[7] =  s * ux + m * uy * uz;
    R[8] = 1.f + m * (-uy * uy - ux * ux);
}

// ---------------- K_batch: rot_mats -> out, pose_feature -> c, joints, chain, A mats
__global__ void k_batch(const float* __restrict__ gp, const float* __restrict__ npo,
                        const float* __restrict__ jp, const float* __restrict__ ep,
                        float* __restrict__ out, float* __restrict__ ws) {
    int b = blockIdx.x * 64 + threadIdx.x;
    if (b >= B_) return;
    float R[5][9];
    rodrigues(gp[b * 3], gp[b * 3 + 1], gp[b * 3 + 2], R[0]);
    rodrigues(npo[b * 3], npo[b * 3 + 1], npo[b * 3 + 2], R[1]);
    rodrigues(jp[b * 3], jp[b * 3 + 1], jp[b * 3 + 2], R[2]);
    rodrigues(ep[b * 6], ep[b * 6 + 1], ep[b * 6 + 2], R[3]);
    rodrigues(ep[b * 6 + 3], ep[b * 6 + 4], ep[b * 6 + 5], R[4]);
    for (int j = 0; j < 5; ++j)
        for (int i = 0; i < 9; ++i)
            out[VOFF + b * 45 + j * 9 + i] = R[j][i];
    for (int j = 1; j < 5; ++j)
        for (int i = 0; i < 9; ++i)
            ws[OFF_C + b * KTOT + 400 + (j - 1) * 9 + i] =
                R[j][i] - ((i == 0 || i == 4 || i == 8) ? 1.f : 0.f);
    // joints = Jt + JS @ betas
    float jt[15];
    for (int q = 0; q < 15; ++q) jt[q] = ws[OFF_JT + q];
    for (int l = 0; l < 400; ++l) {
        float cl = ws[OFF_C + b * KTOT + l];
        #pragma unroll
        for (int q = 0; q < 15; ++q) jt[q] += ws[OFF_JS + q * 400 + l] * cl;
    }
    const int par[5] = {0, 0, 1, 1, 1};
    float rel[5][3];
    for (int k = 0; k < 3; ++k) rel[0][k] = jt[k];
    for (int j = 1; j < 5; ++j)
        for (int k = 0; k < 3; ++k) rel[j][k] = jt[j * 3 + k] - jt[par[j] * 3 + k];
    // kinematic chain (3x4 composition)
    float Rc[5][9], tc[5][3];
    for (int i = 0; i < 9; ++i) Rc[0][i] = R[0][i];
    for (int k = 0; k < 3; ++k) tc[0][k] = rel[0][k];
    for (int j = 1; j < 5; ++j) {
        int p = par[j];
        for (int r = 0; r < 3; ++r) {
            for (int c2 = 0; c2 < 3; ++c2) {
                float s = 0.f;
                for (int m = 0; m < 3; ++m) s += Rc[p][r * 3 + m] * R[j][m * 3 + c2];
                Rc[j][r * 3 + c2] = s;
            }
            float tv = 0.f;
            for (int m = 0; m < 3; ++m) tv += Rc[p][r * 3 + m] * rel[j][m];
            tc[j][r] = tv + tc[p][r];
        }
    }
    // A = [Rc | tc - Rc*joint]
    for (int j = 0; j < 5; ++j)
        for (int r = 0; r < 3; ++r) {
            float tj = 0.f;
            for (int m = 0; m < 3; ++m) tj += Rc[j][r * 3 + m] * jt[j * 3 + m];
            ws[OFF_A + b * 60 + j * 12 + r * 4 + 0] = Rc[j][r * 3 + 0];
            ws[OFF_A + b * 60 + j * 12 + r * 4 + 1] = Rc[j][r * 3 + 1];
            ws[OFF_A + b * 60 + j * 12 + r * 4 + 2] = Rc[j][r * 3 + 2];
            ws[OFF_A + b * 60 + j * 12 + r * 4 + 3] = tc[j][r] - tj;
        }
}

// ---------------- K4: big GEMM (posed offsets) + fused LBS epilogue
// tile: 32 batches x 96 cols (= 32 vertices); K = 440 in 11 chunks of 40
__global__ void __launch_bounds__(256) k_gemm_lbs(
    const float* __restrict__ SD, const float* __restrict__ VT,
    const float* __restrict__ W, const float* __restrict__ ws,
    float* __restrict__ out) {
    __shared__ float As[32 * 44];
    __shared__ float Bs[96 * 44];
    __shared__ float Ps[32 * 96];
    int tid = threadIdx.x;
    int bx = blockIdx.x;             // n-tile
    int by = blockIdx.y;             // b-tile
    int n0 = bx * 96, b0 = by * 32, v0 = bx * 32;
    int ti = tid >> 5;               // 0..7  -> 4 batch rows each
    int tj = tid & 31;               // 0..31 -> 3 n cols each
    float acc[4][3] = {};

    for (int kc = 0; kc < 11; ++kc) {
        for (int s = tid; s < 1280; s += 256) {
            int r = s / 40, cc = s % 40;
            As[r * 44 + cc] = ws[OFF_C + (b0 + r) * KTOT + kc * 40 + cc];
        }
        for (int s = tid; s < 3840; s += 256) {
            int r = s / 40, cc = s % 40;
            int n = n0 + r;
            float v = 0.f;
            if (n < N3) v = (kc < 10) ? SD[n * 400 + kc * 40 + cc]
                                      : ws[OFF_PDT + n * 40 + cc];
            Bs[r * 44 + cc] = v;
        }
        __syncthreads();
        #pragma unroll
        for (int l = 0; l < 40; l += 4) {
            float4 a0 = *reinterpret_cast<const float4*>(&As[(4 * ti + 0) * 44 + l]);
            float4 a1 = *reinterpret_cast<const float4*>(&As[(4 * ti + 1) * 44 + l]);
            float4 a2 = *reinterpret_cast<const float4*>(&As[(4 * ti + 2) * 44 + l]);
            float4 a3 = *reinterpret_cast<const float4*>(&As[(4 * ti + 3) * 44 + l]);
            float4 q0 = *reinterpret_cast<const float4*>(&Bs[(3 * tj + 0) * 44 + l]);
            float4 q1 = *reinterpret_cast<const float4*>(&Bs[(3 * tj + 1) * 44 + l]);
            float4 q2 = *reinterpret_cast<const float4*>(&Bs[(3 * tj + 2) * 44 + l]);
            #define DOT4(A_, Q_, R_, C_) \
                acc[R_][C_] += A_.x * Q_.x + A_.y * Q_.y + A_.z * Q_.z + A_.w * Q_.w
            DOT4(a0, q0, 0, 0); DOT4(a0, q1, 0, 1); DOT4(a0, q2, 0, 2);
            DOT4(a1, q0, 1, 0); DOT4(a1, q1, 1, 1); DOT4(a1, q2, 1, 2);
            DOT4(a2, q0, 2, 0); DOT4(a2, q1, 2, 1); DOT4(a2, q2, 2, 2);
            DOT4(a3, q0, 3, 0); DOT4(a3, q1, 3, 1); DOT4(a3, q2, 3, 2);
            #undef DOT4
        }
        __syncthreads();
    }
    // add v_template, park posed tile in LDS
    #pragma unroll
    for (int rb = 0; rb < 4; ++rb)
        #pragma unroll
        for (int rn = 0; rn < 3; ++rn) {
            int n = n0 + 3 * tj + rn;
            float v = acc[rb][rn];
            if (n < N3) v += VT[n];
            Ps[(4 * ti + rb) * 96 + 3 * tj + rn] = v;
        }
    __syncthreads();
    // LBS epilogue: 32b x 32v pairs, 4 per thread
    for (int q = 0; q < 4; ++q) {
        int p = tid + 256 * q;
        int bl = p >> 5, vl = p & 31;
        int v = v0 + vl;
        if (v < V_) {
            int b = b0 + bl;
            float px = Ps[bl * 96 + 3 * vl + 0];
            float py = Ps[bl * 96 + 3 * vl + 1];
            float pz = Ps[bl * 96 + 3 * vl + 2];
            float T[12];
            #pragma unroll
            for (int i = 0; i < 12; ++i) T[i] = 0.f;
            #pragma unroll
            for (int j = 0; j < 5; ++j) {
                float wj = W[v * 5 + j];
                const float* Ab = &ws[OFF_A + b * 60 + j * 12];
                #pragma unroll
                for (int i = 0; i < 12; ++i) T[i] += wj * Ab[i];
            }
            out[b * N3 + v * 3 + 0] = T[0] * px + T[1] * py + T[2] * pz + T[3];
            out[b * N3 + v * 3 + 1] = T[4] * px + T[5] * py + T[6] * pz + T[7];
            out[b * N3 + v * 3 + 2] = T[8] * px + T[9] * py + T[10] * pz + T[11];
        }
    }
}

extern "C" void kernel_launch(void* const* d_in, const int* in_sizes, int n_in,
                              void* d_out, int out_size, void* d_ws, size_t ws_size,
                              hipStream_t stream) {
    const float* shape = (const float*)d_in[0];
    const float* expr  = (const float*)d_in[1];
    const float* gpose = (const float*)d_in[2];
    const float* npose = (const float*)d_in[3];
    const float* jpose = (const float*)d_in[4];
    const float* epose = (const float*)d_in[5];
    const float* vt    = (const float*)d_in[6];
    const float* sd    = (const float*)d_in[7];
    const float* pd    = (const float*)d_in[8];
    const float* jreg  = (const float*)d_in[9];
    const float* w     = (const float*)d_in[10];
    float* out = (float*)d_out;
    float* ws  = (float*)d_ws;

    k_js_partial<<<dim3(15, 8), 512, 0, stream>>>(jreg, sd, vt, ws);
    k_js_reduce<<<24, 256, 0, stream>>>(ws);
    k_pdt<<<dim3(59, 40), 256, 0, stream>>>(pd, ws);
    k_cbetas<<<(B_ * KTOT + 255) / 256, 256, 0, stream>>>(shape, expr, ws);
    k_batch<<<32, 64, 0, stream>>>(gpose, npose, jpose, epose, out, ws);
    k_gemm_lbs<<<dim3(157, 64), 256, 0, stream>>>(sd, vt, w, ws, out);
}

// Round 2
// 394.087 us; speedup vs baseline: 5.4474x; 5.4474x over previous
//
#include <hip/hip_runtime.h>
#include <hip/hip_bf16.h>
#include <math.h>

#define B_    2048
#define V_    5023
#define N3    15069      // V*3
#define NSE   400        // NS+NE
#define KT    448        // 400 betas + 36 pose_feature + 12 pad
#define VOFF  30861312   // B_*N3, start of rot_mats in d_out

// ws layout (float units)
#define OFF_CB_F   0          // [2048][448] bf16 Cmat  (458752 floats)
#define OFF_SDT_F  458752     // [15069][448] bf16 SDT  (3375456 floats)
#define OFF_JSP    3834208    // [8][15*400] partial JS
#define OFF_JTP    3882208    // [8][15]
#define OFF_JS     3882328    // [15*400]
#define OFF_JT     3888328    // [15]
#define OFF_A      3888344    // [2048][5][12] blended-transform source mats

typedef __attribute__((ext_vector_type(8))) short short8;
typedef __attribute__((ext_vector_type(4))) float f32x4;

// ---------------- K2a: partial JS = Jreg @ shape_dirs, Jt = Jreg @ v_template
__global__ void k_js_partial(const float* __restrict__ Jreg, const float* __restrict__ SD,
                             const float* __restrict__ VT, float* __restrict__ ws) {
    int jk = blockIdx.x;            // 0..14  (j*3+k)
    int ch = blockIdx.y;            // 0..7   v-chunk
    int j = jk / 3, k = jk % 3;
    int t = threadIdx.x;            // 0..511
    int v0 = ch * 628;
    int v1 = min(V_, v0 + 628);
    float acc = 0.f;
    if (t < NSE) {
        for (int v = v0; v < v1; ++v) {
            float jr = Jreg[j * V_ + v];
            acc += jr * SD[(v * 3 + k) * NSE + t];
        }
        ws[OFF_JSP + (ch * 15 + jk) * NSE + t] = acc;
    } else if (t == 511) {
        for (int v = v0; v < v1; ++v) {
            float jr = Jreg[j * V_ + v];
            acc += jr * VT[v * 3 + k];
        }
        ws[OFF_JTP + ch * 15 + jk] = acc;
    }
}

// ---------------- K2c: reduce partials
__global__ void k_js_reduce(float* __restrict__ ws) {
    int t = blockIdx.x * 256 + threadIdx.x;
    if (t < 6000) {
        float s = 0.f;
        for (int ch = 0; ch < 8; ++ch) s += ws[OFF_JSP + ch * 6000 + t];
        ws[OFF_JS + t] = s;
    } else if (t < 6015) {
        int i = t - 6000;
        float s = 0.f;
        for (int ch = 0; ch < 8; ++ch) s += ws[OFF_JTP + ch * 15 + i];
        ws[OFF_JT + i] = s;
    }
}

// ---------------- K_sdt: bf16 B-matrix [15069][448] = [SD | pose_dirs^T | 0]
__global__ void k_sdt(const float* __restrict__ SD, const float* __restrict__ PD,
                      float* __restrict__ ws) {
    int n = blockIdx.x;
    int c = threadIdx.x;            // 0..447
    float v = 0.f;
    if (c < 400) v = SD[n * 400 + c];
    else if (c < 436) v = PD[(c - 400) * N3 + n];
    __hip_bfloat16* sdt = (__hip_bfloat16*)(ws + OFF_SDT_F);
    sdt[n * KT + c] = __float2bfloat16(v);
}

// ---------------- K0: bf16 Cmat[b][0..447] = [shape | expr | 0...] (pose cols later)
__global__ void k_cbetas(const float* __restrict__ sh, const float* __restrict__ ex,
                         float* __restrict__ ws) {
    int f = blockIdx.x * 256 + threadIdx.x;
    if (f >= B_ * KT) return;
    int b = f / KT, l = f % KT;
    float v = 0.f;
    if (l < 300) v = sh[b * 300 + l];
    else if (l < 400) v = ex[b * 100 + (l - 300)];
    __hip_bfloat16* cb = (__hip_bfloat16*)(ws + OFF_CB_F);
    cb[f] = __float2bfloat16(v);
}

// ---------------- rodrigues matching the reference exactly (+1e-8 on components)
__device__ __forceinline__ void rodrigues(float rx, float ry, float rz, float* R) {
    float ax = rx + 1e-8f, ay = ry + 1e-8f, az = rz + 1e-8f;
    float ang = sqrtf(ax * ax + ay * ay + az * az);
    float inv = 1.f / ang;
    float ux = rx * inv, uy = ry * inv, uz = rz * inv;
    float s = sinf(ang), c = cosf(ang), m = 1.f - c;
    R[0] = 1.f + m * (-uz * uz - uy * uy);
    R[1] = -s * uz + m * ux * uy;
    R[2] =  s * uy + m * ux * uz;
    R[3] =  s * uz + m * ux * uy;
    R[4] = 1.f + m * (-uz * uz - ux * ux);
    R[5] = -s * ux + m * uy * uz;
    R[6] = -s * uy + m * ux * uz;
    R[7] =  s * ux + m * uy * uz;
    R[8] = 1.f + m * (-uy * uy - ux * ux);
}

// ---------------- K_batch: rot_mats -> out, pose_feature -> Cmat(bf16), chain, A mats
__global__ void k_batch(const float* __restrict__ gp, const float* __restrict__ npo,
                        const float* __restrict__ jp, const float* __restrict__ ep,
                        const float* __restrict__ sh, const float* __restrict__ ex,
                        float* __restrict__ out, float* __restrict__ ws) {
    int b = blockIdx.x * 64 + threadIdx.x;
    if (b >= B_) return;
    float R[5][9];
    rodrigues(gp[b * 3], gp[b * 3 + 1], gp[b * 3 + 2], R[0]);
    rodrigues(npo[b * 3], npo[b * 3 + 1], npo[b * 3 + 2], R[1]);
    rodrigues(jp[b * 3], jp[b * 3 + 1], jp[b * 3 + 2], R[2]);
    rodrigues(ep[b * 6], ep[b * 6 + 1], ep[b * 6 + 2], R[3]);
    rodrigues(ep[b * 6 + 3], ep[b * 6 + 4], ep[b * 6 + 5], R[4]);
    for (int j = 0; j < 5; ++j)
        for (int i = 0; i < 9; ++i)
            out[VOFF + b * 45 + j * 9 + i] = R[j][i];
    __hip_bfloat16* cb = (__hip_bfloat16*)(ws + OFF_CB_F);
    for (int j = 1; j < 5; ++j)
        for (int i = 0; i < 9; ++i)
            cb[b * KT + 400 + (j - 1) * 9 + i] =
                __float2bfloat16(R[j][i] - ((i == 0 || i == 4 || i == 8) ? 1.f : 0.f));
    // joints = Jt + JS @ betas   (fp32, straight from inputs)
    float jt[15];
    for (int q = 0; q < 15; ++q) jt[q] = ws[OFF_JT + q];
    for (int l = 0; l < 300; ++l) {
        float cl = sh[b * 300 + l];
        #pragma unroll
        for (int q = 0; q < 15; ++q) jt[q] += ws[OFF_JS + q * 400 + l] * cl;
    }
    for (int l = 0; l < 100; ++l) {
        float cl = ex[b * 100 + l];
        #pragma unroll
        for (int q = 0; q < 15; ++q) jt[q] += ws[OFF_JS + q * 400 + 300 + l] * cl;
    }
    const int par[5] = {0, 0, 1, 1, 1};
    float rel[5][3];
    for (int k = 0; k < 3; ++k) rel[0][k] = jt[k];
    for (int j = 1; j < 5; ++j)
        for (int k = 0; k < 3; ++k) rel[j][k] = jt[j * 3 + k] - jt[par[j] * 3 + k];
    float Rc[5][9], tc[5][3];
    for (int i = 0; i < 9; ++i) Rc[0][i] = R[0][i];
    for (int k = 0; k < 3; ++k) tc[0][k] = rel[0][k];
    for (int j = 1; j < 5; ++j) {
        int p = par[j];
        for (int r = 0; r < 3; ++r) {
            for (int c2 = 0; c2 < 3; ++c2) {
                float s = 0.f;
                for (int m = 0; m < 3; ++m) s += Rc[p][r * 3 + m] * R[j][m * 3 + c2];
                Rc[j][r * 3 + c2] = s;
            }
            float tv = 0.f;
            for (int m = 0; m < 3; ++m) tv += Rc[p][r * 3 + m] * rel[j][m];
            tc[j][r] = tv + tc[p][r];
        }
    }
    for (int j = 0; j < 5; ++j)
        for (int r = 0; r < 3; ++r) {
            float tj = 0.f;
            for (int m = 0; m < 3; ++m) tj += Rc[j][r * 3 + m] * jt[j * 3 + m];
            ws[OFF_A + b * 60 + j * 12 + r * 4 + 0] = Rc[j][r * 3 + 0];
            ws[OFF_A + b * 60 + j * 12 + r * 4 + 1] = Rc[j][r * 3 + 1];
            ws[OFF_A + b * 60 + j * 12 + r * 4 + 2] = Rc[j][r * 3 + 2];
            ws[OFF_A + b * 60 + j * 12 + r * 4 + 3] = tc[j][r] - tj;
        }
}

// ---------------- K4: bf16 MFMA GEMM (64b x 96n tile) + fused LBS epilogue
// 4 waves; wave w owns D rows 16w..16w+15, all 96 cols (6 16x16 frags).
// LDS: [Amat 15360B][As 64x72 bf16 = 9216B][Bs 96x72 bf16 = 13824B]
//      Ps (f32 64x97 = 24832B) overlays As/Bs after the K loop.
__global__ void __launch_bounds__(256) k_gemm_lbs(
    const float* __restrict__ VT, const float* __restrict__ W,
    const float* __restrict__ ws, float* __restrict__ out) {
    __shared__ __align__(16) char smem[40192];
    float* Am = (float*)smem;                       // [64][60]
    char* smA = smem + 15360;                       // bf16 [64][72]
    char* smB = smem + 24576;                       // bf16 [96][72]
    float* Ps = (float*)(smem + 15360);             // f32 [64][97]

    const unsigned short* cb  = (const unsigned short*)ws;            // Cmat bf16
    const unsigned short* sdt = (const unsigned short*)(ws + OFF_SDT_F);

    int tid = threadIdx.x;
    int bx = blockIdx.x;             // n-tile (157)
    int by = blockIdx.y;             // b-tile (32)
    int n0 = bx * 96, b0 = by * 64, v0 = bx * 32;
    int w = tid >> 6, l = tid & 63;

    // stage A-mats (fp32) once: [64][60] contiguous
    for (int s = tid; s < 3840; s += 256)
        Am[s] = ws[OFF_A + b0 * 60 + s];

    f32x4 acc[6];
    #pragma unroll
    for (int j = 0; j < 6; ++j) acc[j] = (f32x4){0.f, 0.f, 0.f, 0.f};

    int arow_off = (16 * w + (l & 15)) * 144;
    int koff = (l >> 4) * 16;        // byte offset of this lane's 8-bf16 k-slice

    for (int kc = 0; kc < 7; ++kc) {
        // stage A: 64 rows x 64 bf16 (8 x 16B chunks/row)
        for (int s = tid; s < 512; s += 256) {
            int r = s >> 3, c = s & 7;
            *(uint4*)(smA + r * 144 + c * 16) =
                *(const uint4*)&cb[(b0 + r) * KT + kc * 64 + c * 8];
        }
        // stage B: 96 rows x 64 bf16
        for (int s = tid; s < 768; s += 256) {
            int r = s >> 3, c = s & 7;
            int n = n0 + r;
            uint4 val = {0u, 0u, 0u, 0u};
            if (n < N3) val = *(const uint4*)&sdt[n * KT + kc * 64 + c * 8];
            *(uint4*)(smB + r * 144 + c * 16) = val;
        }
        __syncthreads();
        #pragma unroll
        for (int ks = 0; ks < 2; ++ks) {
            short8 af = *(const short8*)(smA + arow_off + ks * 64 + koff);
            #pragma unroll
            for (int j = 0; j < 6; ++j) {
                short8 bf = *(const short8*)(smB + (16 * j + (l & 15)) * 144 + ks * 64 + koff);
                acc[j] = __builtin_amdgcn_mfma_f32_16x16x32_bf16(af, bf, acc[j], 0, 0, 0);
            }
        }
        __syncthreads();
    }

    // acc + v_template -> Ps (overlays As/Bs; safe after trailing sync)
    #pragma unroll
    for (int j = 0; j < 6; ++j) {
        int col = 16 * j + (l & 15);
        int n = n0 + col;
        float vt0 = (n < N3) ? VT[n] : 0.f;
        #pragma unroll
        for (int i = 0; i < 4; ++i) {
            int row = 16 * w + 4 * (l >> 4) + i;
            Ps[row * 97 + col] = acc[j][i] + vt0;
        }
    }
    __syncthreads();

    // LBS epilogue: 64b x 32v pairs; each thread keeps one v, walks 8 b's
    int vl = tid & 31, v = v0 + vl;
    bool vok = v < V_;
    float w5[5] = {0.f, 0.f, 0.f, 0.f, 0.f};
    if (vok)
        #pragma unroll
        for (int j = 0; j < 5; ++j) w5[j] = W[v * 5 + j];
    for (int q = 0; q < 8; ++q) {
        int bl = (tid >> 5) + 8 * q;
        float px = Ps[bl * 97 + 3 * vl + 0];
        float py = Ps[bl * 97 + 3 * vl + 1];
        float pz = Ps[bl * 97 + 3 * vl + 2];
        if (vok) {
            float T[12];
            #pragma unroll
            for (int i = 0; i < 12; ++i) T[i] = 0.f;
            #pragma unroll
            for (int j = 0; j < 5; ++j) {
                const float* Aj = &Am[bl * 60 + j * 12];
                #pragma unroll
                for (int i = 0; i < 12; ++i) T[i] += w5[j] * Aj[i];
            }
            int ob = (b0 + bl) * N3 + v * 3;
            out[ob + 0] = T[0] * px + T[1] * py + T[2] * pz + T[3];
            out[ob + 1] = T[4] * px + T[5] * py + T[6] * pz + T[7];
            out[ob + 2] = T[8] * px + T[9] * py + T[10] * pz + T[11];
        }
    }
}

extern "C" void kernel_launch(void* const* d_in, const int* in_sizes, int n_in,
                              void* d_out, int out_size, void* d_ws, size_t ws_size,
                              hipStream_t stream) {
    const float* shape = (const float*)d_in[0];
    const float* expr  = (const float*)d_in[1];
    const float* gpose = (const float*)d_in[2];
    const float* npose = (const float*)d_in[3];
    const float* jpose = (const float*)d_in[4];
    const float* epose = (const float*)d_in[5];
    const float* vt    = (const float*)d_in[6];
    const float* sd    = (const float*)d_in[7];
    const float* pd    = (const float*)d_in[8];
    const float* jreg  = (const float*)d_in[9];
    const float* w     = (const float*)d_in[10];
    float* out = (float*)d_out;
    float* ws  = (float*)d_ws;

    k_js_partial<<<dim3(15, 8), 512, 0, stream>>>(jreg, sd, vt, ws);
    k_js_reduce<<<24, 256, 0, stream>>>(ws);
    k_sdt<<<N3, KT, 0, stream>>>(sd, pd, ws);
    k_cbetas<<<(B_ * KT + 255) / 256, 256, 0, stream>>>(shape, expr, ws);
    k_batch<<<32, 64, 0, stream>>>(gpose, npose, jpose, epose, shape, expr, out, ws);
    k_gemm_lbs<<<dim3(157, 32), 256, 0, stream>>>(vt, w, ws, out);
}

// Round 3
// 264.409 us; speedup vs baseline: 8.1191x; 1.4904x over previous
//
#include <hip/hip_runtime.h>
#include <hip/hip_bf16.h>
#include <math.h>

#define B_    2048
#define V_    5023
#define N3    15069      // V*3
#define KT    448        // 400 betas + 36 pose_feature + 12 pad
#define VOFF  30861312   // B_*N3, start of rot_mats in d_out
#define NCH   64
#define CHV   79

// ws layout (float units)
#define OFF_CB_F   0          // [2048][448] bf16 Cmat (458752 floats); JSP overlays this pre-k_cbetas
#define OFF_JSP    0          // [64][6016] partials: [0..5999]=JS, [6000..6014]=Jt
#define OFF_SDT_F  458752     // [15069][448] bf16 SDT (3375456 floats)
#define OFF_JS     3834208    // [15*400]
#define OFF_JT     3840208    // [15]
#define OFF_A      3840224    // [2048][5][12] blended-transform source mats

typedef __attribute__((ext_vector_type(8))) short short8;
typedef __attribute__((ext_vector_type(4))) float f32x4;

// ---------------- K1: fused — stream SD once: build bf16 SDT + partial JS/Jt
__global__ void __launch_bounds__(512) k_js_sdt(
    const float* __restrict__ Jreg, const float* __restrict__ SD,
    const float* __restrict__ PD, const float* __restrict__ VT,
    float* __restrict__ ws) {
    int ch = blockIdx.x;
    int v0 = ch * CHV, v1 = min(V_, v0 + CHV);
    int nv = v1 - v0;
    int t = threadIdx.x;
    __shared__ float jw[5][CHV];
    for (int s = t; s < 5 * CHV; s += 512) {
        int j = s / CHV, vi = s % CHV;
        jw[j][vi] = (v0 + vi < V_) ? Jreg[j * V_ + v0 + vi] : 0.f;
    }
    __syncthreads();
    __hip_bfloat16* sdt = (__hip_bfloat16*)(ws + OFF_SDT_F);
    if (t < 400) {
        float acc[15];
        #pragma unroll
        for (int i = 0; i < 15; ++i) acc[i] = 0.f;
        for (int vi = 0; vi < nv; ++vi) {
            int v = v0 + vi;
            float s0 = SD[(v * 3 + 0) * 400 + t];
            float s1 = SD[(v * 3 + 1) * 400 + t];
            float s2 = SD[(v * 3 + 2) * 400 + t];
            sdt[(v * 3 + 0) * KT + t] = __float2bfloat16(s0);
            sdt[(v * 3 + 1) * KT + t] = __float2bfloat16(s1);
            sdt[(v * 3 + 2) * KT + t] = __float2bfloat16(s2);
            #pragma unroll
            for (int j = 0; j < 5; ++j) {
                float jr = jw[j][vi];
                acc[j * 3 + 0] += jr * s0;
                acc[j * 3 + 1] += jr * s1;
                acc[j * 3 + 2] += jr * s2;
            }
        }
        #pragma unroll
        for (int i = 0; i < 15; ++i)
            ws[OFF_JSP + ch * 6016 + i * 400 + t] = acc[i];
    } else if (t < 436) {
        int p = t - 400;
        for (int vi = 0; vi < nv; ++vi) {
            int n = (v0 + vi) * 3;
            sdt[(n + 0) * KT + 400 + p] = __float2bfloat16(PD[p * N3 + n + 0]);
            sdt[(n + 1) * KT + 400 + p] = __float2bfloat16(PD[p * N3 + n + 1]);
            sdt[(n + 2) * KT + 400 + p] = __float2bfloat16(PD[p * N3 + n + 2]);
        }
    } else if (t < 448) {
        __hip_bfloat16 z = __float2bfloat16(0.f);
        for (int vi = 0; vi < nv; ++vi) {
            int n = (v0 + vi) * 3;
            sdt[(n + 0) * KT + t] = z;
            sdt[(n + 1) * KT + t] = z;
            sdt[(n + 2) * KT + t] = z;
        }
    } else if (t < 463) {
        int jk = t - 448, j = jk / 3, k = jk % 3;
        float a = 0.f;
        for (int vi = 0; vi < nv; ++vi)
            a += jw[j][vi] * VT[(v0 + vi) * 3 + k];
        ws[OFF_JSP + ch * 6016 + 6000 + jk] = a;
    }
}

// ---------------- K2: reduce partials (deterministic)
__global__ void k_js_reduce(float* __restrict__ ws) {
    int t = blockIdx.x * 256 + threadIdx.x;
    if (t >= 6016) return;
    float s = 0.f;
    for (int ch = 0; ch < NCH; ++ch) s += ws[OFF_JSP + ch * 6016 + t];
    if (t < 6000) ws[OFF_JS + t] = s;
    else if (t < 6015) ws[OFF_JT + (t - 6000)] = s;
}

// ---------------- K0: bf16 Cmat[b][0..447] = [shape | expr | 0...] (pose cols later)
__global__ void k_cbetas(const float* __restrict__ sh, const float* __restrict__ ex,
                         float* __restrict__ ws) {
    int f = blockIdx.x * 256 + threadIdx.x;
    if (f >= B_ * KT) return;
    int b = f / KT, l = f % KT;
    float v = 0.f;
    if (l < 300) v = sh[b * 300 + l];
    else if (l < 400) v = ex[b * 100 + (l - 300)];
    __hip_bfloat16* cb = (__hip_bfloat16*)(ws + OFF_CB_F);
    cb[f] = __float2bfloat16(v);
}

// ---------------- rodrigues matching the reference exactly (+1e-8 on components)
__device__ __forceinline__ void rodrigues(float rx, float ry, float rz, float* R) {
    float ax = rx + 1e-8f, ay = ry + 1e-8f, az = rz + 1e-8f;
    float ang = sqrtf(ax * ax + ay * ay + az * az);
    float inv = 1.f / ang;
    float ux = rx * inv, uy = ry * inv, uz = rz * inv;
    float s = sinf(ang), c = cosf(ang), m = 1.f - c;
    R[0] = 1.f + m * (-uz * uz - uy * uy);
    R[1] = -s * uz + m * ux * uy;
    R[2] =  s * uy + m * ux * uz;
    R[3] =  s * uz + m * ux * uy;
    R[4] = 1.f + m * (-uz * uz - ux * ux);
    R[5] = -s * ux + m * uy * uz;
    R[6] = -s * uy + m * ux * uz;
    R[7] =  s * ux + m * uy * uz;
    R[8] = 1.f + m * (-uy * uy - ux * ux);
}

// ---------------- K_batch: rot_mats -> out, pose_feature -> Cmat(bf16), chain, A mats
__global__ void k_batch(const float* __restrict__ gp, const float* __restrict__ npo,
                        const float* __restrict__ jp, const float* __restrict__ ep,
                        const float* __restrict__ sh, const float* __restrict__ ex,
                        float* __restrict__ out, float* __restrict__ ws) {
    int b = blockIdx.x * 64 + threadIdx.x;
    if (b >= B_) return;
    float R[5][9];
    rodrigues(gp[b * 3], gp[b * 3 + 1], gp[b * 3 + 2], R[0]);
    rodrigues(npo[b * 3], npo[b * 3 + 1], npo[b * 3 + 2], R[1]);
    rodrigues(jp[b * 3], jp[b * 3 + 1], jp[b * 3 + 2], R[2]);
    rodrigues(ep[b * 6], ep[b * 6 + 1], ep[b * 6 + 2], R[3]);
    rodrigues(ep[b * 6 + 3], ep[b * 6 + 4], ep[b * 6 + 5], R[4]);
    for (int j = 0; j < 5; ++j)
        for (int i = 0; i < 9; ++i)
            out[VOFF + b * 45 + j * 9 + i] = R[j][i];
    __hip_bfloat16* cb = (__hip_bfloat16*)(ws + OFF_CB_F);
    for (int j = 1; j < 5; ++j)
        for (int i = 0; i < 9; ++i)
            cb[b * KT + 400 + (j - 1) * 9 + i] =
                __float2bfloat16(R[j][i] - ((i == 0 || i == 4 || i == 8) ? 1.f : 0.f));
    // joints = Jt + JS @ betas   (fp32, straight from inputs)
    float jt[15];
    #pragma unroll
    for (int q = 0; q < 15; ++q) jt[q] = ws[OFF_JT + q];
    for (int l = 0; l < 300; ++l) {
        float cl = sh[b * 300 + l];
        #pragma unroll
        for (int q = 0; q < 15; ++q) jt[q] += ws[OFF_JS + q * 400 + l] * cl;
    }
    for (int l = 0; l < 100; ++l) {
        float cl = ex[b * 100 + l];
        #pragma unroll
        for (int q = 0; q < 15; ++q) jt[q] += ws[OFF_JS + q * 400 + 300 + l] * cl;
    }
    const int par[5] = {0, 0, 1, 1, 1};
    float rel[5][3];
    for (int k = 0; k < 3; ++k) rel[0][k] = jt[k];
    for (int j = 1; j < 5; ++j)
        for (int k = 0; k < 3; ++k) rel[j][k] = jt[j * 3 + k] - jt[par[j] * 3 + k];
    float Rc[5][9], tc[5][3];
    for (int i = 0; i < 9; ++i) Rc[0][i] = R[0][i];
    for (int k = 0; k < 3; ++k) tc[0][k] = rel[0][k];
    for (int j = 1; j < 5; ++j) {
        int p = par[j];
        for (int r = 0; r < 3; ++r) {
            for (int c2 = 0; c2 < 3; ++c2) {
                float s = 0.f;
                for (int m = 0; m < 3; ++m) s += Rc[p][r * 3 + m] * R[j][m * 3 + c2];
                Rc[j][r * 3 + c2] = s;
            }
            float tv = 0.f;
            for (int m = 0; m < 3; ++m) tv += Rc[p][r * 3 + m] * rel[j][m];
            tc[j][r] = tv + tc[p][r];
        }
    }
    for (int j = 0; j < 5; ++j)
        for (int r = 0; r < 3; ++r) {
            float tj = 0.f;
            for (int m = 0; m < 3; ++m) tj += Rc[j][r * 3 + m] * jt[j * 3 + m];
            ws[OFF_A + b * 60 + j * 12 + r * 4 + 0] = Rc[j][r * 3 + 0];
            ws[OFF_A + b * 60 + j * 12 + r * 4 + 1] = Rc[j][r * 3 + 1];
            ws[OFF_A + b * 60 + j * 12 + r * 4 + 2] = Rc[j][r * 3 + 2];
            ws[OFF_A + b * 60 + j * 12 + r * 4 + 3] = tc[j][r] - tj;
        }
}

// ---------------- K4: bf16 MFMA GEMM (64b x 96n tile) + fused LBS epilogue
__global__ void __launch_bounds__(256) k_gemm_lbs(
    const float* __restrict__ VT, const float* __restrict__ W,
    const float* __restrict__ ws, float* __restrict__ out) {
    __shared__ __align__(16) char smem[40192];
    float* Am = (float*)smem;                       // [64][60]
    char* smA = smem + 15360;                       // bf16 [64][72]
    char* smB = smem + 24576;                       // bf16 [96][72]
    float* Ps = (float*)(smem + 15360);             // f32 [64][97]

    const unsigned short* cb  = (const unsigned short*)ws;            // Cmat bf16
    const unsigned short* sdt = (const unsigned short*)(ws + OFF_SDT_F);

    int tid = threadIdx.x;
    int bx = blockIdx.x;             // n-tile (157)
    int by = blockIdx.y;             // b-tile (32)
    int n0 = bx * 96, b0 = by * 64, v0 = bx * 32;
    int w = tid >> 6, l = tid & 63;

    for (int s = tid; s < 3840; s += 256)
        Am[s] = ws[OFF_A + b0 * 60 + s];

    f32x4 acc[6];
    #pragma unroll
    for (int j = 0; j < 6; ++j) acc[j] = (f32x4){0.f, 0.f, 0.f, 0.f};

    int arow_off = (16 * w + (l & 15)) * 144;
    int koff = (l >> 4) * 16;

    for (int kc = 0; kc < 7; ++kc) {
        for (int s = tid; s < 512; s += 256) {
            int r = s >> 3, c = s & 7;
            *(uint4*)(smA + r * 144 + c * 16) =
                *(const uint4*)&cb[(b0 + r) * KT + kc * 64 + c * 8];
        }
        for (int s = tid; s < 768; s += 256) {
            int r = s >> 3, c = s & 7;
            int n = n0 + r;
            uint4 val = {0u, 0u, 0u, 0u};
            if (n < N3) val = *(const uint4*)&sdt[n * KT + kc * 64 + c * 8];
            *(uint4*)(smB + r * 144 + c * 16) = val;
        }
        __syncthreads();
        #pragma unroll
        for (int ks = 0; ks < 2; ++ks) {
            short8 af = *(const short8*)(smA + arow_off + ks * 64 + koff);
            #pragma unroll
            for (int j = 0; j < 6; ++j) {
                short8 bf = *(const short8*)(smB + (16 * j + (l & 15)) * 144 + ks * 64 + koff);
                acc[j] = __builtin_amdgcn_mfma_f32_16x16x32_bf16(af, bf, acc[j], 0, 0, 0);
            }
        }
        __syncthreads();
    }

    #pragma unroll
    for (int j = 0; j < 6; ++j) {
        int col = 16 * j + (l & 15);
        int n = n0 + col;
        float vt0 = (n < N3) ? VT[n] : 0.f;
        #pragma unroll
        for (int i = 0; i < 4; ++i) {
            int row = 16 * w + 4 * (l >> 4) + i;
            Ps[row * 97 + col] = acc[j][i] + vt0;
        }
    }
    __syncthreads();

    int vl = tid & 31, v = v0 + vl;
    bool vok = v < V_;
    float w5[5] = {0.f, 0.f, 0.f, 0.f, 0.f};
    if (vok)
        #pragma unroll
        for (int j = 0; j < 5; ++j) w5[j] = W[v * 5 + j];
    for (int q = 0; q < 8; ++q) {
        int bl = (tid >> 5) + 8 * q;
        float px = Ps[bl * 97 + 3 * vl + 0];
        float py = Ps[bl * 97 + 3 * vl + 1];
        float pz = Ps[bl * 97 + 3 * vl + 2];
        if (vok) {
            float T[12];
            #pragma unroll
            for (int i = 0; i < 12; ++i) T[i] = 0.f;
            #pragma unroll
            for (int j = 0; j < 5; ++j) {
                const float* Aj = &Am[bl * 60 + j * 12];
                #pragma unroll
                for (int i = 0; i < 12; ++i) T[i] += w5[j] * Aj[i];
            }
            int ob = (b0 + bl) * N3 + v * 3;
            out[ob + 0] = T[0] * px + T[1] * py + T[2] * pz + T[3];
            out[ob + 1] = T[4] * px + T[5] * py + T[6] * pz + T[7];
            out[ob + 2] = T[8] * px + T[9] * py + T[10] * pz + T[11];
        }
    }
}

extern "C" void kernel_launch(void* const* d_in, const int* in_sizes, int n_in,
                              void* d_out, int out_size, void* d_ws, size_t ws_size,
                              hipStream_t stream) {
    const float* shape = (const float*)d_in[0];
    const float* expr  = (const float*)d_in[1];
    const float* gpose = (const float*)d_in[2];
    const float* npose = (const float*)d_in[3];
    const float* jpose = (const float*)d_in[4];
    const float* epose = (const float*)d_in[5];
    const float* vt    = (const float*)d_in[6];
    const float* sd    = (const float*)d_in[7];
    const float* pd    = (const float*)d_in[8];
    const float* jreg  = (const float*)d_in[9];
    const float* w     = (const float*)d_in[10];
    float* out = (float*)d_out;
    float* ws  = (float*)d_ws;

    k_js_sdt<<<NCH, 512, 0, stream>>>(jreg, sd, pd, vt, ws);
    k_js_reduce<<<24, 256, 0, stream>>>(ws);
    k_cbetas<<<(B_ * KT + 255) / 256, 256, 0, stream>>>(shape, expr, ws);
    k_batch<<<32, 64, 0, stream>>>(gpose, npose, jpose, epose, shape, expr, out, ws);
    k_gemm_lbs<<<dim3(157, 32), 256, 0, stream>>>(vt, w, ws, out);
}

// Round 4
// 202.056 us; speedup vs baseline: 10.6246x; 1.3086x over previous
//
#include <hip/hip_runtime.h>
#include <hip/hip_bf16.h>
#include <math.h>

#define B_    2048
#define V_    5023
#define N3    15069      // V*3
#define VOFF  30861312   // B_*N3, start of rot_mats in d_out

// GEMM geometry: block = 256 rows x 96 cols, 4 waves (each 64 rows), BK=32
#define BM    256
#define BN    96
#define NKC   14         // 448/32
#define NBX   157
#define NBY   8

// ws layout (float units)
#define OFF_CBT    0           // bf16 Cmat tiled: 8*14*16KB = 1835008 B = 458752 f
#define OFF_SDTT   458752      // bf16 SDT tiled: 157*14*6KB = 13504512 B = 3376128 f
#define OFF_JSP    0           // overlay: [6016][256] partials (consumed before CBT/SDTT written)
#define OFF_JS     3834880     // [15*400]
#define OFF_JT     3840880     // [15]
#define OFF_A      3840896     // [2048][60]

#define NCH 256
#define CHV 20

typedef __attribute__((ext_vector_type(8))) short short8;
typedef __attribute__((ext_vector_type(4))) float f32x4;

typedef __attribute__((address_space(1))) const void gvoid_t;
typedef __attribute__((address_space(3))) void lvoid_t;
#define GLDS16(g, l) __builtin_amdgcn_global_load_lds((gvoid_t*)(g), (lvoid_t*)(l), 16, 0, 0)

// ---------------- K1: JS/Jt partials; SD streamed exactly once, 256 blocks
__global__ void __launch_bounds__(512) k_js(
    const float* __restrict__ Jreg, const float* __restrict__ SD,
    const float* __restrict__ VT, float* __restrict__ ws) {
    int ch = blockIdx.x;
    int v0 = ch * CHV;
    int t = threadIdx.x;
    __shared__ float jw[5][CHV];
    for (int s = t; s < 5 * CHV; s += 512) {
        int j = s / CHV, vi = s % CHV;
        int v = v0 + vi;
        jw[j][vi] = (v < V_) ? Jreg[j * V_ + v] : 0.f;
    }
    __syncthreads();
    int nv = min(V_ - v0, CHV);          // may be <= 0 (trailing chunks)
    if (t < 400) {
        float acc[15];
        #pragma unroll
        for (int i = 0; i < 15; ++i) acc[i] = 0.f;
        for (int vi = 0; vi < nv; ++vi) {
            int v = v0 + vi;
            float s0 = SD[(v * 3 + 0) * 400 + t];
            float s1 = SD[(v * 3 + 1) * 400 + t];
            float s2 = SD[(v * 3 + 2) * 400 + t];
            #pragma unroll
            for (int j = 0; j < 5; ++j) {
                float jr = jw[j][vi];
                acc[j * 3 + 0] += jr * s0;
                acc[j * 3 + 1] += jr * s1;
                acc[j * 3 + 2] += jr * s2;
            }
        }
        #pragma unroll
        for (int i = 0; i < 15; ++i)
            ws[OFF_JSP + (i * 400 + t) * NCH + ch] = acc[i];
    } else if (t >= 448 && t < 463) {
        int jk = t - 448, j = jk / 3, k = jk % 3;
        float a = 0.f;
        for (int vi = 0; vi < nv; ++vi)
            a += jw[j][vi] * VT[(v0 + vi) * 3 + k];
        ws[OFF_JSP + (6000 + jk) * NCH + ch] = a;
    }
}

// ---------------- K2: reduce partials (transposed layout -> contiguous float4)
__global__ void k_js_reduce(float* __restrict__ ws) {
    int r = blockIdx.x * 256 + threadIdx.x;
    if (r >= 6016) return;
    const float4* p = (const float4*)&ws[OFF_JSP + r * NCH];
    float4 s4 = {0.f, 0.f, 0.f, 0.f};
    for (int i = 0; i < NCH / 4; ++i) {
        float4 v = p[i];
        s4.x += v.x; s4.y += v.y; s4.z += v.z; s4.w += v.w;
    }
    float s = s4.x + s4.y + s4.z + s4.w;
    if (r < 6000) ws[OFF_JS + r] = s;
    else if (r < 6015) ws[OFF_JT + (r - 6000)] = s;
}

// ---------------- K3: SDT in MFMA-fragment-tiled order, coalesced 16B stores
// chunk id = ((bx*14 + kc)*6 + j)*64 + lane ; element (n,k):
//   n = bx*96 + j*16 + (lane&15), k = kc*32 + (lane>>4)*8 + e
__global__ void k_sdt_tiled(const float* __restrict__ SD, const float* __restrict__ PD,
                            float* __restrict__ ws) {
    int id = blockIdx.x * 256 + threadIdx.x;
    if (id >= NBX * NKC * 6 * 64) return;
    int lane = id & 63;
    int t = id >> 6;
    int j = t % 6; t /= 6;
    int kc = t % NKC, bx = t / NKC;
    int n = bx * 96 + j * 16 + (lane & 15);
    int k0 = kc * 32 + (lane >> 4) * 8;
    union { __hip_bfloat16 h[8]; uint4 u; } pk;
    if (n < N3 && k0 + 8 <= 400) {
        const float4* s = (const float4*)&SD[n * 400 + k0];
        float4 a = s[0], b = s[1];
        pk.h[0] = __float2bfloat16(a.x); pk.h[1] = __float2bfloat16(a.y);
        pk.h[2] = __float2bfloat16(a.z); pk.h[3] = __float2bfloat16(a.w);
        pk.h[4] = __float2bfloat16(b.x); pk.h[5] = __float2bfloat16(b.y);
        pk.h[6] = __float2bfloat16(b.z); pk.h[7] = __float2bfloat16(b.w);
    } else {
        #pragma unroll
        for (int e = 0; e < 8; ++e) {
            int k = k0 + e;
            float v = 0.f;
            if (n < N3) {
                if (k < 400) v = SD[n * 400 + k];
                else if (k < 436) v = PD[(k - 400) * N3 + n];
            }
            pk.h[e] = __float2bfloat16(v);
        }
    }
    ((uint4*)((char*)ws + OFF_SDTT * 4))[id] = pk.u;
}

// ---------------- K4: Cmat (betas part) in fragment-tiled order
// chunk id = ((by*14 + kc)*16 + mf)*64 + lane ; b = by*256+mf*16+(lane&15)
__global__ void k_cbt_tiled(const float* __restrict__ sh, const float* __restrict__ ex,
                            float* __restrict__ ws) {
    int id = blockIdx.x * 256 + threadIdx.x;
    if (id >= NBY * NKC * 16 * 64) return;
    int lane = id & 63;
    int t = id >> 6;
    int mf = t & 15; t >>= 4;
    int kc = t % NKC, by = t / NKC;
    int b = by * BM + mf * 16 + (lane & 15);
    int k0 = kc * 32 + (lane >> 4) * 8;
    union { __hip_bfloat16 h[8]; uint4 u; } pk;
    #pragma unroll
    for (int e = 0; e < 8; ++e) {
        int k = k0 + e;
        float v = 0.f;
        if (k < 300) v = sh[b * 300 + k];
        else if (k < 400) v = ex[b * 100 + (k - 300)];
        pk.h[e] = __float2bfloat16(v);
    }
    ((uint4*)ws)[id] = pk.u;
}

__device__ __forceinline__ int cbt_idx(int b, int k) {
    int by = b >> 8, mf = (b & 255) >> 4, cr = b & 15;
    int kc = k >> 5, kg = (k & 31) >> 3, e = k & 7;
    return (((by * NKC + kc) * 16 + mf) * 64 + kg * 16 + cr) * 8 + e;
}

// ---------------- rodrigues matching the reference exactly (+1e-8 on components)
__device__ __forceinline__ void rodrigues(float rx, float ry, float rz, float* R) {
    float ax = rx + 1e-8f, ay = ry + 1e-8f, az = rz + 1e-8f;
    float ang = sqrtf(ax * ax + ay * ay + az * az);
    float inv = 1.f / ang;
    float ux = rx * inv, uy = ry * inv, uz = rz * inv;
    float s = sinf(ang), c = cosf(ang), m = 1.f - c;
    R[0] = 1.f + m * (-uz * uz - uy * uy);
    R[1] = -s * uz + m * ux * uy;
    R[2] =  s * uy + m * ux * uz;
    R[3] =  s * uz + m * ux * uy;
    R[4] = 1.f + m * (-uz * uz - ux * ux);
    R[5] = -s * ux + m * uy * uz;
    R[6] = -s * uy + m * ux * uz;
    R[7] =  s * ux + m * uy * uz;
    R[8] = 1.f + m * (-uy * uy - ux * ux);
}

// ---------------- K5: rot_mats -> out, pose cols -> tiled Cmat, chain, A mats
__global__ void k_batch(const float* __restrict__ gp, const float* __restrict__ npo,
                        const float* __restrict__ jp, const float* __restrict__ ep,
                        const float* __restrict__ sh, const float* __restrict__ ex,
                        float* __restrict__ out, float* __restrict__ ws) {
    int b = blockIdx.x * 64 + threadIdx.x;
    if (b >= B_) return;
    float R[5][9];
    rodrigues(gp[b * 3], gp[b * 3 + 1], gp[b * 3 + 2], R[0]);
    rodrigues(npo[b * 3], npo[b * 3 + 1], npo[b * 3 + 2], R[1]);
    rodrigues(jp[b * 3], jp[b * 3 + 1], jp[b * 3 + 2], R[2]);
    rodrigues(ep[b * 6], ep[b * 6 + 1], ep[b * 6 + 2], R[3]);
    rodrigues(ep[b * 6 + 3], ep[b * 6 + 4], ep[b * 6 + 5], R[4]);
    for (int j = 0; j < 5; ++j)
        for (int i = 0; i < 9; ++i)
            out[VOFF + b * 45 + j * 9 + i] = R[j][i];
    __hip_bfloat16* cb = (__hip_bfloat16*)ws;
    for (int j = 1; j < 5; ++j)
        for (int i = 0; i < 9; ++i)
            cb[cbt_idx(b, 400 + (j - 1) * 9 + i)] =
                __float2bfloat16(R[j][i] - ((i == 0 || i == 4 || i == 8) ? 1.f : 0.f));
    float jt[15];
    #pragma unroll
    for (int q = 0; q < 15; ++q) jt[q] = ws[OFF_JT + q];
    for (int l = 0; l < 300; ++l) {
        float cl = sh[b * 300 + l];
        #pragma unroll
        for (int q = 0; q < 15; ++q) jt[q] += ws[OFF_JS + q * 400 + l] * cl;
    }
    for (int l = 0; l < 100; ++l) {
        float cl = ex[b * 100 + l];
        #pragma unroll
        for (int q = 0; q < 15; ++q) jt[q] += ws[OFF_JS + q * 400 + 300 + l] * cl;
    }
    const int par[5] = {0, 0, 1, 1, 1};
    float rel[5][3];
    for (int k = 0; k < 3; ++k) rel[0][k] = jt[k];
    for (int j = 1; j < 5; ++j)
        for (int k = 0; k < 3; ++k) rel[j][k] = jt[j * 3 + k] - jt[par[j] * 3 + k];
    float Rc[5][9], tc[5][3];
    for (int i = 0; i < 9; ++i) Rc[0][i] = R[0][i];
    for (int k = 0; k < 3; ++k) tc[0][k] = rel[0][k];
    for (int j = 1; j < 5; ++j) {
        int p = par[j];
        for (int r = 0; r < 3; ++r) {
            for (int c2 = 0; c2 < 3; ++c2) {
                float s = 0.f;
                for (int m = 0; m < 3; ++m) s += Rc[p][r * 3 + m] * R[j][m * 3 + c2];
                Rc[j][r * 3 + c2] = s;
            }
            float tv = 0.f;
            for (int m = 0; m < 3; ++m) tv += Rc[p][r * 3 + m] * rel[j][m];
            tc[j][r] = tv + tc[p][r];
        }
    }
    for (int j = 0; j < 5; ++j)
        for (int r = 0; r < 3; ++r) {
            float tj = 0.f;
            for (int m = 0; m < 3; ++m) tj += Rc[j][r * 3 + m] * jt[j * 3 + m];
            ws[OFF_A + b * 60 + j * 12 + r * 4 + 0] = Rc[j][r * 3 + 0];
            ws[OFF_A + b * 60 + j * 12 + r * 4 + 1] = Rc[j][r * 3 + 1];
            ws[OFF_A + b * 60 + j * 12 + r * 4 + 2] = Rc[j][r * 3 + 2];
            ws[OFF_A + b * 60 + j * 12 + r * 4 + 3] = tc[j][r] - tj;
        }
}

// ---------------- K6: MFMA GEMM, global_load_lds + double-buffer + counted vmcnt
// 4 waves, wave w owns rows 64w..64w+63 (4 mfrags), 96 cols (6 frags).
// LDS: [A0 16K][B0 6K][A1 16K][B1 6K] = 45056 B; Ps f32[128][98] = 50176 B overlay.
__global__ void __launch_bounds__(256, 3) k_gemm_lbs(
    const float* __restrict__ VT, const float* __restrict__ W,
    const float* __restrict__ ws, float* __restrict__ out) {
    __shared__ __align__(16) char smem[50176];

    const char* cbt  = (const char*)ws;
    const char* sdtt = (const char*)ws + (size_t)OFF_SDTT * 4;
    const float* Amat = ws + OFF_A;

    // bijective XCD-chunked swizzle: 1256 = 8 * 157
    int flat = blockIdx.x;
    int nid = (flat & 7) * 157 + (flat >> 3);
    int bx = nid >> 3, by = nid & 7;
    int n0 = bx * BN, b0 = by * BM, v0 = bx * 32;

    int tid = threadIdx.x;
    int w = tid >> 6, lane = tid & 63;

    const char* Aglb = cbt + (size_t)(by * NKC) * 16384;
    const char* Bglb = sdtt + (size_t)(bx * NKC) * 6144;

    // stage kc into parity buffer p: A 16 chunks (4/wave), B 6 chunks (waves 0-2: 2)
    auto stage = [&](int kc, int p) {
        char* lA = smem + p * 22528;
        char* lB = lA + 16384;
        const char* ga = Aglb + (size_t)kc * 16384;
        const char* gb = Bglb + (size_t)kc * 6144;
        #pragma unroll
        for (int c = 0; c < 4; ++c) {
            int ch = 4 * w + c;
            GLDS16(ga + ch * 1024 + lane * 16, lA + ch * 1024);
        }
        if (w < 3) {
            #pragma unroll
            for (int c = 0; c < 2; ++c) {
                int ch = 2 * w + c;
                GLDS16(gb + ch * 1024 + lane * 16, lB + ch * 1024);
            }
        }
    };

    asm volatile("s_waitcnt vmcnt(0)" ::: "memory");
    stage(0, 0);
    stage(1, 1);

    f32x4 acc[4][6];
    #pragma unroll
    for (int m = 0; m < 4; ++m)
        #pragma unroll
        for (int j = 0; j < 6; ++j) acc[m][j] = (f32x4){0.f, 0.f, 0.f, 0.f};

    for (int kc = 0; kc < NKC; ++kc) {
        int p = kc & 1;
        if (kc < NKC - 1) {          // next tile's loads stay in flight
            if (w < 3) asm volatile("s_waitcnt vmcnt(6)" ::: "memory");
            else       asm volatile("s_waitcnt vmcnt(4)" ::: "memory");
        } else {
            asm volatile("s_waitcnt vmcnt(0)" ::: "memory");
        }
        __builtin_amdgcn_s_barrier();
        const char* lA = smem + p * 22528;
        const char* lB = lA + 16384;
        short8 af[4];
        #pragma unroll
        for (int m = 0; m < 4; ++m)
            af[m] = *(const short8*)(lA + (4 * w + m) * 1024 + lane * 16);
        #pragma unroll
        for (int j = 0; j < 6; ++j) {
            short8 bf = *(const short8*)(lB + j * 1024 + lane * 16);
            #pragma unroll
            for (int m = 0; m < 4; ++m)
                acc[m][j] = __builtin_amdgcn_mfma_f32_16x16x32_bf16(af[m], bf, acc[m][j], 0, 0, 0);
        }
        __builtin_amdgcn_s_barrier();
        if (kc + 2 < NKC) stage(kc + 2, p);
    }

    // epilogue: v_template add, LBS blend; two 128-row halves through Ps
    float vt6[6];
    #pragma unroll
    for (int j = 0; j < 6; ++j) {
        int n = n0 + 16 * j + (lane & 15);
        vt6[j] = (n < N3) ? VT[n] : 0.f;
    }
    int vl = tid & 31, v = v0 + vl;
    bool vok = v < V_;
    float w5[5] = {0.f, 0.f, 0.f, 0.f, 0.f};
    if (vok)
        #pragma unroll
        for (int j = 0; j < 5; ++j) w5[j] = W[v * 5 + j];

    float* Ps = (float*)smem;
    #pragma unroll
    for (int h = 0; h < 2; ++h) {
        __builtin_amdgcn_s_barrier();
        if ((w >> 1) == h) {
            #pragma unroll
            for (int j = 0; j < 6; ++j) {
                int col = 16 * j + (lane & 15);
                #pragma unroll
                for (int m = 0; m < 4; ++m) {
                    int lrow = 64 * (w & 1) + 16 * m + 4 * (lane >> 4);
                    #pragma unroll
                    for (int i = 0; i < 4; ++i)
                        Ps[(lrow + i) * 98 + col] = acc[m][j][i] + vt6[j];
                }
            }
        }
        __builtin_amdgcn_s_barrier();
        for (int q = 0; q < 16; ++q) {
            int bl = (tid >> 5) + 8 * q;
            float px = Ps[bl * 98 + 3 * vl + 0];
            float py = Ps[bl * 98 + 3 * vl + 1];
            float pz = Ps[bl * 98 + 3 * vl + 2];
            if (vok) {
                int b = b0 + 128 * h + bl;
                const float4* Aq = (const float4*)&Amat[b * 60];
                float4 t0 = {0,0,0,0}, t1 = {0,0,0,0}, t2 = {0,0,0,0};
                #pragma unroll
                for (int j = 0; j < 5; ++j) {
                    float wj = w5[j];
                    float4 a0 = Aq[j * 3 + 0], a1 = Aq[j * 3 + 1], a2 = Aq[j * 3 + 2];
                    t0.x += wj * a0.x; t0.y += wj * a0.y; t0.z += wj * a0.z; t0.w += wj * a0.w;
                    t1.x += wj * a1.x; t1.y += wj * a1.y; t1.z += wj * a1.z; t1.w += wj * a1.w;
                    t2.x += wj * a2.x; t2.y += wj * a2.y; t2.z += wj * a2.z; t2.w += wj * a2.w;
                }
                int ob = b * N3 + v * 3;
                out[ob + 0] = t0.x * px + t0.y * py + t0.z * pz + t0.w;
                out[ob + 1] = t1.x * px + t1.y * py + t1.z * pz + t1.w;
                out[ob + 2] = t2.x * px + t2.y * py + t2.z * pz + t2.w;
            }
        }
    }
}

extern "C" void kernel_launch(void* const* d_in, const int* in_sizes, int n_in,
                              void* d_out, int out_size, void* d_ws, size_t ws_size,
                              hipStream_t stream) {
    const float* shape = (const float*)d_in[0];
    const float* expr  = (const float*)d_in[1];
    const float* gpose = (const float*)d_in[2];
    const float* npose = (const float*)d_in[3];
    const float* jpose = (const float*)d_in[4];
    const float* epose = (const float*)d_in[5];
    const float* vt    = (const float*)d_in[6];
    const float* sd    = (const float*)d_in[7];
    const float* pd    = (const float*)d_in[8];
    const float* jreg  = (const float*)d_in[9];
    const float* w     = (const float*)d_in[10];
    float* out = (float*)d_out;
    float* ws  = (float*)d_ws;

    k_js<<<NCH, 512, 0, stream>>>(jreg, sd, vt, ws);
    k_js_reduce<<<24, 256, 0, stream>>>(ws);
    k_sdt_tiled<<<(NBX * NKC * 6 * 64 + 255) / 256, 256, 0, stream>>>(sd, pd, ws);
    k_cbt_tiled<<<(NBY * NKC * 16 * 64 + 255) / 256, 256, 0, stream>>>(shape, expr, ws);
    k_batch<<<32, 64, 0, stream>>>(gpose, npose, jpose, epose, shape, expr, out, ws);
    k_gemm_lbs<<<NBX * NBY, 256, 0, stream>>>(vt, w, ws, out);
}